// Round 7
// baseline (201.997 us; speedup 1.0000x reference)
//
#include <hip/hip_runtime.h>

// B=4, NQ=NKV=2048, d=512, H=8, DH=64, M = B*NQ = 8192
#define LOG2E 1.44269504088896f
#define CS (0.125f * LOG2E)

typedef __bf16 bf16x8 __attribute__((ext_vector_type(8)));
typedef float f32x4 __attribute__((ext_vector_type(4)));
typedef float f32x16 __attribute__((ext_vector_type(16)));
typedef unsigned short u16x8 __attribute__((ext_vector_type(8)));

// raw v_exp_f32 (inputs are bounded softmax logits; library denormal guards not needed)
#if __has_builtin(__builtin_amdgcn_exp2f)
#define fexp2(x) __builtin_amdgcn_exp2f(x)
#else
extern "C" __device__ float __ocml_native_exp2_f32(float);
#define fexp2(x) __ocml_native_exp2_f32(x)
#endif

__device__ __forceinline__ unsigned short f2bf(float f) {
  union { float f; unsigned int u; } v{f};
  unsigned int r = v.u + 0x7fffu + ((v.u >> 16) & 1u);   // RNE
  return (unsigned short)(r >> 16);
}
__device__ __forceinline__ float bf2f(unsigned short u) {
  union { unsigned int u; float f; } v; v.u = ((unsigned int)u) << 16; return v.f;
}
// pack two positive floats to bf16x2: round-half-up + v_perm high-half merge
__device__ __forceinline__ unsigned int pkr(float a, float b) {
  unsigned int ua = __builtin_bit_cast(unsigned int, a) + 0x8000u;
  unsigned int ub = __builtin_bit_cast(unsigned int, b) + 0x8000u;
  return __builtin_amdgcn_perm(ub, ua, 0x07060302);  // (hi16(ub)<<16)|hi16(ua)
}

// swap upper 32 lanes of x with lower 32 lanes of y (both updated)
#define PLSWAP(x, y) asm("v_permlane32_swap_b32 %0, %1" : "+v"(x), "+v"(y))

// async global->LDS, 16B per lane; LDS dest must be wave-uniform base + lane*16
typedef __attribute__((address_space(3))) unsigned int lds32_t;
typedef const __attribute__((address_space(1))) unsigned int glb32_t;
__device__ __forceinline__ void gld16(const unsigned short* g, unsigned short* l) {
  __builtin_amdgcn_global_load_lds((glb32_t*)(unsigned long long)g,
                                   (lds32_t*)(unsigned int)(unsigned long long)l,
                                   16, 0, 0);
}

// ---- fused converts: activations fp32->bf16 (blocks 0..12287) + weight
// ---- transpose via LDS tile (blocks 12288..12543); Wq scaled by CS ----
__global__ __launch_bounds__(256) void conv_all(
    const float* __restrict__ xq, const float* __restrict__ xk, const float* __restrict__ xv,
    const float* __restrict__ Wq, const float* __restrict__ Wk,
    const float* __restrict__ Wv, const float* __restrict__ Wo,
    unsigned short* __restrict__ oxq, unsigned short* __restrict__ oxk, unsigned short* __restrict__ oxv,
    unsigned short* __restrict__ oWq, unsigned short* __restrict__ oWk,
    unsigned short* __restrict__ oWv, unsigned short* __restrict__ oWo) {
  __shared__ unsigned short T[64 * 65];
  const int blk = blockIdx.x;
  if (blk < 12288) {
    const int N4 = (8192 * 512) / 4;
    int idx = blk * 256 + threadIdx.x;
    const float* src; unsigned short* dst; int i;
    if (idx < N4)          { src = xq; dst = oxq; i = idx; }
    else if (idx < 2 * N4) { src = xk; dst = oxk; i = idx - N4; }
    else                   { src = xv; dst = oxv; i = idx - 2 * N4; }
    float4 v = ((const float4*)src)[i];
    ushort4 o; o.x = f2bf(v.x); o.y = f2bf(v.y); o.z = f2bf(v.z); o.w = f2bf(v.w);
    ((ushort4*)dst)[i] = o;
  } else {
    const int wblk = blk - 12288;
    const int wsel = wblk >> 6;
    const int tile = wblk & 63;
    const int tk = (tile >> 3) * 64, tn = (tile & 7) * 64;
    const float* src = (wsel == 0) ? Wq : (wsel == 1) ? Wk : (wsel == 2) ? Wv : Wo;
    unsigned short* dst = (wsel == 0) ? oWq : (wsel == 1) ? oWk : (wsel == 2) ? oWv : oWo;
    const float scale = (wsel == 0) ? CS : 1.0f;
    const int rr = threadIdx.x >> 4;
    const int cc = (threadIdx.x & 15) * 4;
#pragma unroll
    for (int i = 0; i < 4; i++) {
      int row = rr + i * 16;
      float4 v = *(const float4*)&src[(size_t)(tk + row) * 512 + tn + cc];
      T[(cc + 0) * 65 + row] = f2bf(v.x * scale);
      T[(cc + 1) * 65 + row] = f2bf(v.y * scale);
      T[(cc + 2) * 65 + row] = f2bf(v.z * scale);
      T[(cc + 3) * 65 + row] = f2bf(v.w * scale);
    }
    __syncthreads();
#pragma unroll
    for (int i = 0; i < 4; i++) {
      int n = rr + i * 16;
      ushort4 o;
      o.x = T[n * 65 + cc + 0]; o.y = T[n * 65 + cc + 1];
      o.z = T[n * 65 + cc + 2]; o.w = T[n * 65 + cc + 3];
      *(ushort4*)&dst[(size_t)(tn + n) * 512 + tk + cc] = o;
    }
  }
}

// ---- m97-style GEMM mainloop: 128x128 tile, BK=32, double-buffered staging ----
__device__ __forceinline__ void gemm_tile(
    const unsigned short* __restrict__ A, const unsigned short* __restrict__ Bt,
    int rowBlk, int colBlk, unsigned short* As, unsigned short* Bs, f32x4 (&acc)[4][4]) {
  const int t = threadIdx.x;
  const int lane = t & 63, c = lane & 15, g = lane >> 4;
  const int w = t >> 6;
  const int wm = w & 1, wn = w >> 1;
#pragma unroll
  for (int i = 0; i < 4; i++)
#pragma unroll
    for (int j = 0; j < 4; j++)
#pragma unroll
      for (int r = 0; r < 4; r++) acc[i][j][r] = 0.f;

  const int sr = t >> 2, sch = t & 3;   // staging row/chunk for idx=t
#define STAGE_PROJ(kkk, buf)                                                     \
  do {                                                                           \
    unsigned short* Ad = As + (buf) * (128 * 32);                                \
    unsigned short* Bd = Bs + (buf) * (128 * 32);                                \
    gld16(&A[(size_t)(rowBlk + sr) * 512 + (kkk) + sch * 8], &Ad[t * 8]);        \
    gld16(&Bt[(size_t)(colBlk + sr) * 512 + (kkk) + sch * 8], &Bd[t * 8]);       \
    gld16(&A[(size_t)(rowBlk + sr + 64) * 512 + (kkk) + sch * 8],                \
          &Ad[(t + 256) * 8]);                                                   \
    gld16(&Bt[(size_t)(colBlk + sr + 64) * 512 + (kkk) + sch * 8],               \
          &Bd[(t + 256) * 8]);                                                   \
  } while (0)

  STAGE_PROJ(0, 0);
  __syncthreads();   // prologue drain

  for (int kt = 0; kt < 16; kt++) {
    if (kt < 15) STAGE_PROJ((kt + 1) * 32, (kt + 1) & 1);
    const unsigned short* Ac = As + (kt & 1) * (128 * 32);
    const unsigned short* Bc = Bs + (kt & 1) * (128 * 32);
    bf16x8 af[4], bfr[4];
#pragma unroll
    for (int i = 0; i < 4; i++)
      af[i] = __builtin_bit_cast(bf16x8, *(const u16x8*)&Ac[(wm * 64 + i * 16 + c) * 32 + g * 8]);
#pragma unroll
    for (int j = 0; j < 4; j++)
      bfr[j] = __builtin_bit_cast(bf16x8, *(const u16x8*)&Bc[(wn * 64 + j * 16 + c) * 32 + g * 8]);
#pragma unroll
    for (int i = 0; i < 4; i++)
#pragma unroll
      for (int j = 0; j < 4; j++)
        acc[i][j] = __builtin_amdgcn_mfma_f32_16x16x32_bf16(af[i], bfr[j], acc[i][j], 0, 0, 0);
    if (kt < 15) __syncthreads();
  }
#undef STAGE_PROJ
}

// ---- all 5 projections in one dispatch: grid (64, 20) ----
__global__ __launch_bounds__(256) void proj_all(
    const unsigned short* __restrict__ xq, const unsigned short* __restrict__ xk,
    const unsigned short* __restrict__ xv,
    const unsigned short* __restrict__ Wq, const unsigned short* __restrict__ Wk,
    const unsigned short* __restrict__ Wv,
    unsigned short* __restrict__ Qo, unsigned short* __restrict__ XKo,
    unsigned short* __restrict__ XVo, unsigned short* __restrict__ Ko,
    unsigned short* __restrict__ Vto) {
  __shared__ unsigned short As[2 * 128 * 32];
  __shared__ unsigned short Bs[2 * 128 * 32];
  const int rowBlk = blockIdx.x * 128;
  const int y = blockIdx.y;
  const unsigned short* A; const unsigned short* Bt; int colBlk; int mode;
  unsigned short* out;
  if (y < 12) {
    int wsel = y >> 2;
    A = xq; colBlk = (y & 3) * 128; mode = 0;
    Bt = (wsel == 0) ? Wq : (wsel == 1) ? Wk : Wv;
    out = (wsel == 0) ? Qo : (wsel == 1) ? XKo : XVo;
  } else if (y < 16) {
    A = xk; Bt = Wk; out = Ko; colBlk = (y - 12) * 128; mode = 0;
  } else {
    A = xv; Bt = Wv; out = Vto; colBlk = (y - 16) * 128; mode = 1;
  }
  f32x4 acc[4][4];
  gemm_tile(A, Bt, rowBlk, colBlk, As, Bs, acc);
  const int t = threadIdx.x;
  const int w = t >> 6, lane = t & 63, c = lane & 15, g = lane >> 4;
  const int wm = w & 1, wn = w >> 1;
  if (mode == 0) {
#pragma unroll
    for (int i = 0; i < 4; i++)
#pragma unroll
      for (int j = 0; j < 4; j++)
#pragma unroll
        for (int r = 0; r < 4; r++) {
          int row = rowBlk + wm * 64 + i * 16 + g * 4 + r;
          int col = colBlk + wn * 64 + j * 16 + c;
          out[(size_t)row * 512 + col] = f2bf(acc[i][j][r]);
        }
  } else {
    // Vt[b][h][dh][n]: acc[i][j][0..3] are 4 consecutive tokens n at fixed dh
#pragma unroll
    for (int i = 0; i < 4; i++) {
      int tok0 = rowBlk + wm * 64 + i * 16 + g * 4;   // tokens tok0..tok0+3
      int bb = tok0 >> 11, n0 = tok0 & 2047;
#pragma unroll
      for (int j = 0; j < 4; j++) {
        int col = colBlk + wn * 64 + j * 16 + c;       // h*64+dh
        int hh = col >> 6, dh = col & 63;
        ushort4 o;
        o.x = f2bf(acc[i][j][0]); o.y = f2bf(acc[i][j][1]);
        o.z = f2bf(acc[i][j][2]); o.w = f2bf(acc[i][j][3]);
        *(ushort4*)&out[((size_t)(bb * 8 + hh) * 64 + dh) * 2048 + n0] = o;
      }
    }
  }
}

// ---- out GEMM: Ob @ Wo^T + bias -> f32: 128x64 tiles, double-buffered ----
__global__ __launch_bounds__(256) void gemm_out(
    const unsigned short* __restrict__ A, const unsigned short* __restrict__ Bt,
    float* __restrict__ out, const float* __restrict__ bias) {
  __shared__ unsigned short As[2 * 128 * 32];
  __shared__ unsigned short Bs[2 * 64 * 32];
  const int rowBlk = blockIdx.x * 128;
  const int colBlk = blockIdx.y * 64;
  const int t = threadIdx.x;
  const int lane = t & 63, c = lane & 15, g = lane >> 4;
  const int w = t >> 6;
  const int wm = w & 1, wn = w >> 1;   // waves 2x2 over (64 rows x 32 cols)
  f32x4 acc[4][2];
#pragma unroll
  for (int i = 0; i < 4; i++)
#pragma unroll
    for (int j = 0; j < 2; j++)
#pragma unroll
      for (int r = 0; r < 4; r++) acc[i][j][r] = 0.f;

  const int sr = t >> 2, sch = t & 3;
#define STAGE_OUT(kkk, buf)                                                      \
  do {                                                                           \
    unsigned short* Ad = As + (buf) * (128 * 32);                                \
    unsigned short* Bd = Bs + (buf) * (64 * 32);                                 \
    gld16(&A[(size_t)(rowBlk + sr) * 512 + (kkk) + sch * 8], &Ad[t * 8]);        \
    gld16(&A[(size_t)(rowBlk + sr + 64) * 512 + (kkk) + sch * 8],                \
          &Ad[(t + 256) * 8]);                                                   \
    gld16(&Bt[(size_t)(colBlk + sr) * 512 + (kkk) + sch * 8], &Bd[t * 8]);       \
  } while (0)

  STAGE_OUT(0, 0);
  __syncthreads();

  for (int kt = 0; kt < 16; kt++) {
    if (kt < 15) STAGE_OUT((kt + 1) * 32, (kt + 1) & 1);
    const unsigned short* Ac = As + (kt & 1) * (128 * 32);
    const unsigned short* Bc = Bs + (kt & 1) * (64 * 32);
    bf16x8 af[4], bfr[2];
#pragma unroll
    for (int i = 0; i < 4; i++)
      af[i] = __builtin_bit_cast(bf16x8, *(const u16x8*)&Ac[(wm * 64 + i * 16 + c) * 32 + g * 8]);
#pragma unroll
    for (int j = 0; j < 2; j++)
      bfr[j] = __builtin_bit_cast(bf16x8, *(const u16x8*)&Bc[(wn * 32 + j * 16 + c) * 32 + g * 8]);
#pragma unroll
    for (int i = 0; i < 4; i++)
#pragma unroll
      for (int j = 0; j < 2; j++)
        acc[i][j] = __builtin_amdgcn_mfma_f32_16x16x32_bf16(af[i], bfr[j], acc[i][j], 0, 0, 0);
    if (kt < 15) __syncthreads();
  }
#undef STAGE_OUT
#pragma unroll
  for (int i = 0; i < 4; i++)
#pragma unroll
    for (int j = 0; j < 2; j++)
#pragma unroll
      for (int r = 0; r < 4; r++) {
        int row = rowBlk + wm * 64 + i * 16 + g * 4 + r;
        int col = colBlk + wn * 32 + j * 16 + c;
        out[(size_t)row * 512 + col] = acc[i][j][r] + bias[col];
      }
}

// ---- fused flash attention v8: v6b math (verified) + split-K x2 for TLP.
// 512 blocks x 512 thr = 8 waves: w01 = w&3 picks 32-q sub-tile, wk = w>>2
// picks K-half (kt 0..15 vs 16..31). 4096 waves = 4/SIMD (v4-level TLP) vs
// v6b's 2/SIMD. Staging covers BOTH halves per iteration (4 gld16/thread);
// sync = ONE __syncthreads per kt (v6b skeleton, compiler-managed drains —
// NO raw barriers / counted vmcnt after v7's race).  After the loop, wk=1
// waves deposit (accO, lq) into the dead K/V LDS at stride 33 (bank-spread);
// wk=0 waves accumulate and run the v6b epilogue. XCD pin: id&7 = h.
__global__ __launch_bounds__(512, 2) void attn_kernel(
    const unsigned short* __restrict__ Q, const unsigned short* __restrict__ K,
    const unsigned short* __restrict__ Vt, const unsigned short* __restrict__ XK,
    const unsigned short* __restrict__ XV, unsigned short* __restrict__ O) {
  __shared__ unsigned short Ks[2][2][64 * 64];   // [khalf][dbuf][key][dh-slot]
  __shared__ unsigned short Vs[2][2][64 * 64];   // [khalf][dbuf][dh][key-slot]
  __shared__ float Fin[4][2][32];                // per-q-wave epilogue broadcast
  const int t = threadIdx.x;
  const int w = t >> 6, lane = t & 63;
  const int w01 = w & 3, wk = w >> 2;
  const int rowA = lane & 31, hi = lane >> 5, l7 = lane & 7;
  const int id = blockIdx.x;                     // 512 blocks; XCD = id&7 = h
  const int h = id & 7, qt = (id >> 3) & 15, b = id >> 7;
  const size_t hb = (size_t)b * (2048 * 512) + h * 64;
  const size_t vhb = (size_t)(b * 8 + h) * 64 * 2048;
  const int qb0 = qt * 128 + w01 * 32;

  // staging: thread t -> row sr, swizzled 8-elem slot (sch ^ sr&7)  [v6b proven]
  const int sr = t >> 3, sch = t & 7;
  const int ssl = (sch ^ (sr & 7)) * 8;
  const size_t kgoff = hb + (size_t)sr * 512 + ssl;
  const size_t vgoff = vhb + (size_t)sr * 2048 + ssl;

  // Q fragments (B-operand): Q[q = qb0+rowA][dh = d*16 + hi*8 + e]
  bf16x8 qf[4];
#pragma unroll
  for (int d = 0; d < 4; d++)
    qf[d] = __builtin_bit_cast(bf16x8,
        *(const u16x8*)&Q[hb + (size_t)(qb0 + rowA) * 512 + d * 16 + hi * 8]);

  f32x16 accO[2];
#pragma unroll
  for (int n = 0; n < 2; n++)
#pragma unroll
    for (int r = 0; r < 16; r++) accO[n][r] = 0.f;
  float lq = 0.f;

  // prologue: stage tile 0 (half 0) and tile 16 (half 1) into dbuf 0
  gld16(&K[kgoff], &Ks[0][0][t * 8]);
  gld16(&K[kgoff + (size_t)16 * (64 * 512)], &Ks[1][0][t * 8]);
  gld16(&Vt[vgoff], &Vs[0][0][t * 8]);
  gld16(&Vt[vgoff + 16 * 64], &Vs[1][0][t * 8]);
  __syncthreads();

  for (int kt = 0; kt < 16; kt++) {
    const int cb = kt & 1;
    if (kt < 15) {
      gld16(&K[kgoff + (size_t)(kt + 1) * (64 * 512)], &Ks[0][cb ^ 1][t * 8]);
      gld16(&K[kgoff + (size_t)(kt + 17) * (64 * 512)], &Ks[1][cb ^ 1][t * 8]);
      gld16(&Vt[vgoff + (size_t)(kt + 1) * 64], &Vs[0][cb ^ 1][t * 8]);
      gld16(&Vt[vgoff + (size_t)(kt + 17) * 64], &Vs[1][cb ^ 1][t * 8]);
    }
    const unsigned short* Kc = &Ks[wk][cb][0];
    const unsigned short* Vc = &Vs[wk][cb][0];

    // QK^T: s0 = keys 0-31, s1 = keys 32-63 of this wave's tile; q = rowA
    f32x16 s0, s1;
#pragma unroll
    for (int r = 0; r < 16; r++) { s0[r] = 0.f; s1[r] = 0.f; }
    __builtin_amdgcn_s_setprio(1);
#pragma unroll
    for (int d = 0; d < 4; d++) {
      bf16x8 k0 = __builtin_bit_cast(bf16x8,
          *(const u16x8*)&Kc[rowA * 64 + (((d * 2 + hi) ^ l7) * 8)]);
      s0 = __builtin_amdgcn_mfma_f32_32x32x16_bf16(k0, qf[d], s0, 0, 0, 0);
    }
#pragma unroll
    for (int d = 0; d < 4; d++) {
      bf16x8 k1 = __builtin_bit_cast(bf16x8,
          *(const u16x8*)&Kc[(32 + rowA) * 64 + (((d * 2 + hi) ^ l7) * 8)]);
      s1 = __builtin_amdgcn_mfma_f32_32x32x16_bf16(k1, qf[d], s1, 0, 0, 0);
    }
    __builtin_amdgcn_s_setprio(0);

    // exp in place + row-partial sum (lane-local; q fixed per lane)
    float sum = 0.f;
#pragma unroll
    for (int r = 0; r < 16; r++) { s0[r] = fexp2(s0[r]); sum += s0[r]; }
#pragma unroll
    for (int r = 0; r < 16; r++) { s1[r] = fexp2(s1[r]); sum += s1[r]; }
    lq += sum;

    // P->A-frag (pkr + permlane32_swap) and PV, per 32-key sub-tile
#define PVSUB(P, T2)                                                            \
  {                                                                             \
    unsigned int x0 = pkr(P[0], P[1]),   y0 = pkr(P[4], P[5]);                  \
    unsigned int x1 = pkr(P[2], P[3]),   y1 = pkr(P[6], P[7]);                  \
    unsigned int x2 = pkr(P[8], P[9]),   y2 = pkr(P[12], P[13]);                \
    unsigned int x3 = pkr(P[10], P[11]), y3 = pkr(P[14], P[15]);                \
    PLSWAP(x0, y0); PLSWAP(x1, y1); PLSWAP(x2, y2); PLSWAP(x3, y3);             \
    uint4 w0 = {x0, x1, y0, y1};                                                \
    uint4 w1 = {x2, x3, y2, y3};                                                \
    bf16x8 pa0 = __builtin_bit_cast(bf16x8, w0);                                \
    bf16x8 pa1 = __builtin_bit_cast(bf16x8, w1);                                \
    _Pragma("unroll")                                                           \
    for (int n = 0; n < 2; n++) {                                               \
      bf16x8 v0 = __builtin_bit_cast(bf16x8,                                    \
          *(const u16x8*)&Vc[(n * 32 + rowA) * 64 + ((((T2) * 4 + hi) ^ l7) * 8)]); \
      bf16x8 v1 = __builtin_bit_cast(bf16x8,                                    \
          *(const u16x8*)&Vc[(n * 32 + rowA) * 64 + ((((T2) * 4 + 2 + hi) ^ l7) * 8)]); \
      accO[n] = __builtin_amdgcn_mfma_f32_32x32x16_bf16(pa0, v0, accO[n], 0, 0, 0); \
      accO[n] = __builtin_amdgcn_mfma_f32_32x32x16_bf16(pa1, v1, accO[n], 0, 0, 0); \
    }                                                                           \
  }
    __builtin_amdgcn_s_setprio(1);
    PVSUB(s0, 0);
    PVSUB(s1, 1);
    __builtin_amdgcn_s_setprio(0);
#undef PVSUB

    if (kt < 15) __syncthreads();
  }

  // all waves done reading K/V LDS before the merge overwrites it
  __syncthreads();

  // ---- split-K merge: wk=1 deposits into dead K/V LDS, wk=0 accumulates ----
  {
    float* MB = (w01 < 2) ? (float*)&Ks[0][0][0] : (float*)&Vs[0][0][0];
    const int mbase = ((w01 & 1) * 64 + lane) * 33;   // stride 33: lane->bank spread
    if (wk == 1) {
#pragma unroll
      for (int n = 0; n < 2; n++)
#pragma unroll
        for (int reg = 0; reg < 16; reg++) MB[mbase + n * 16 + reg] = accO[n][reg];
      MB[mbase + 32] = lq;
    }
    __syncthreads();
    if (wk == 1) return;   // wave-uniform exit; no barriers after this point
#pragma unroll
    for (int n = 0; n < 2; n++)
#pragma unroll
      for (int reg = 0; reg < 16; reg++) accO[n][reg] += MB[mbase + n * 16 + reg];
    lq += MB[mbase + 32];
  }

  // finish row-sum: other hi-half holds the remaining keys' partials
  lq += __shfl_xor(lq, 32);

  // diagonal term: q . xq_k over dh=64 ONLY; split by hi (32 elems each)
  float part = 0.f;
  {
    const size_t base = hb + (size_t)(qb0 + rowA) * 512 + hi * 32;
#pragma unroll
    for (int ii = 0; ii < 4; ii++) {
      u16x8 q8 = *(const u16x8*)&Q[base + ii * 8];
      u16x8 x8 = *(const u16x8*)&XK[base + ii * 8];
#pragma unroll
      for (int e = 0; e < 8; e++) part += bf2f(q8[e]) * bf2f(x8[e]);
    }
  }
  part += __shfl_xor(part, 32);
  float pd = fexp2(part);
  float inv = 1.f / (lq + pd);
  if (lane < 32) {
    Fin[w01][0][rowA] = inv;
    Fin[w01][1][rowA] = pd * inv;
  }
  __builtin_amdgcn_s_waitcnt(0);   // per-wave LDS RAW (same-wave ordering)

  f32x4 inva[4], pia[4];
#pragma unroll
  for (int rq = 0; rq < 4; rq++) {
    inva[rq] = *(const f32x4*)&Fin[w01][0][rq * 8 + hi * 4];
    pia[rq]  = *(const f32x4*)&Fin[w01][1][rq * 8 + hi * 4];
  }
#pragma unroll
  for (int n = 0; n < 2; n++)
#pragma unroll
    for (int reg = 0; reg < 16; reg++) {
      const int rq = reg >> 2, r = reg & 3;
      const int q = rq * 8 + hi * 4 + r;          // crow(reg, hi)
      const int qrow = qb0 + q;
      float xv = bf2f(XV[hb + (size_t)qrow * 512 + n * 32 + rowA]);
      float val = accO[n][reg] * inva[rq][r] + pia[rq][r] * xv;
      O[((size_t)(b * 2048 + qrow)) * 512 + h * 64 + n * 32 + rowA] = f2bf(val);
    }
}

extern "C" void kernel_launch(void* const* d_in, const int* in_sizes, int n_in,
                              void* d_out, int out_size, void* d_ws, size_t ws_size,
                              hipStream_t stream) {
  const float* xq = (const float*)d_in[0];
  const float* xk = (const float*)d_in[1];
  const float* xv = (const float*)d_in[2];
  const float* Wq = (const float*)d_in[3];
  const float* Wk = (const float*)d_in[4];
  const float* Wv = (const float*)d_in[5];
  const float* Wo = (const float*)d_in[6];
  const float* bo = (const float*)d_in[7];

  unsigned short* ws = (unsigned short*)d_ws;
  const size_t MD = 8192ull * 512;
  const size_t WD = 512ull * 512;
  unsigned short* xq_b = ws;
  unsigned short* xk_b = xq_b + MD;
  unsigned short* xv_b = xk_b + MD;
  unsigned short* Wq_t = xv_b + MD;
  unsigned short* Wk_t = Wq_t + WD;
  unsigned short* Wv_t = Wk_t + WD;
  unsigned short* Wo_t = Wv_t + WD;
  unsigned short* Qb  = Wo_t + WD;
  unsigned short* Kb  = Qb + MD;
  unsigned short* Vtb = Kb + MD;
  unsigned short* XKb = Vtb + MD;
  unsigned short* XVb = XKb + MD;
  unsigned short* Ob  = XVb + MD;
  // 9*MD + 4*WD elems = ~74 MB

  conv_all<<<dim3(12544), 256, 0, stream>>>(xq, xk, xv, Wq, Wk, Wv, Wo,
                                            xq_b, xk_b, xv_b, Wq_t, Wk_t, Wv_t, Wo_t);
  proj_all<<<dim3(64, 20), 256, 0, stream>>>(xq_b, xk_b, xv_b, Wq_t, Wk_t, Wv_t,
                                             Qb, XKb, XVb, Kb, Vtb);
  attn_kernel<<<dim3(512), 512, 0, stream>>>(Qb, Kb, Vtb, XKb, XVb, Ob);
  gemm_out<<<dim3(64, 8), 256, 0, stream>>>(Ob, Wo_t, (float*)d_out, bo);
}

// Round 8
// 191.874 us; speedup vs baseline: 1.0528x; 1.0528x over previous
//
#include <hip/hip_runtime.h>

// B=4, NQ=NKV=2048, d=512, H=8, DH=64, M = B*NQ = 8192
#define LOG2E 1.44269504088896f
#define CS (0.125f * LOG2E)

typedef __bf16 bf16x8 __attribute__((ext_vector_type(8)));
typedef float f32x4 __attribute__((ext_vector_type(4)));
typedef float f32x16 __attribute__((ext_vector_type(16)));
typedef unsigned short u16x8 __attribute__((ext_vector_type(8)));

// raw v_exp_f32 (inputs are bounded softmax logits; library denormal guards not needed)
#if __has_builtin(__builtin_amdgcn_exp2f)
#define fexp2(x) __builtin_amdgcn_exp2f(x)
#else
extern "C" __device__ float __ocml_native_exp2_f32(float);
#define fexp2(x) __ocml_native_exp2_f32(x)
#endif

__device__ __forceinline__ unsigned short f2bf(float f) {
  union { float f; unsigned int u; } v{f};
  unsigned int r = v.u + 0x7fffu + ((v.u >> 16) & 1u);   // RNE
  return (unsigned short)(r >> 16);
}
__device__ __forceinline__ float bf2f(unsigned short u) {
  union { unsigned int u; float f; } v; v.u = ((unsigned int)u) << 16; return v.f;
}
// pack two positive floats to bf16x2: round-half-up + v_perm high-half merge
__device__ __forceinline__ unsigned int pkr(float a, float b) {
  unsigned int ua = __builtin_bit_cast(unsigned int, a) + 0x8000u;
  unsigned int ub = __builtin_bit_cast(unsigned int, b) + 0x8000u;
  return __builtin_amdgcn_perm(ub, ua, 0x07060302);  // (hi16(ub)<<16)|hi16(ua)
}

// swap upper 32 lanes of x with lower 32 lanes of y (both updated)
#define PLSWAP(x, y) asm("v_permlane32_swap_b32 %0, %1" : "+v"(x), "+v"(y))

// async global->LDS, 16B per lane; LDS dest must be wave-uniform base + lane*16
typedef __attribute__((address_space(3))) unsigned int lds32_t;
typedef const __attribute__((address_space(1))) unsigned int glb32_t;
__device__ __forceinline__ void gld16(const unsigned short* g, unsigned short* l) {
  __builtin_amdgcn_global_load_lds((glb32_t*)(unsigned long long)g,
                                   (lds32_t*)(unsigned int)(unsigned long long)l,
                                   16, 0, 0);
}

// ---- weights only: transpose via LDS tile + fp32->bf16; 256 blocks ----
__global__ __launch_bounds__(256) void conv_w(
    const float* __restrict__ Wq, const float* __restrict__ Wk,
    const float* __restrict__ Wv, const float* __restrict__ Wo,
    unsigned short* __restrict__ oWq, unsigned short* __restrict__ oWk,
    unsigned short* __restrict__ oWv, unsigned short* __restrict__ oWo) {
  __shared__ unsigned short T[64 * 65];
  const int wblk = blockIdx.x;
  const int wsel = wblk >> 6;
  const int tile = wblk & 63;
  const int tk = (tile >> 3) * 64, tn = (tile & 7) * 64;
  const float* src = (wsel == 0) ? Wq : (wsel == 1) ? Wk : (wsel == 2) ? Wv : Wo;
  unsigned short* dst = (wsel == 0) ? oWq : (wsel == 1) ? oWk : (wsel == 2) ? oWv : oWo;
  const int rr = threadIdx.x >> 4;
  const int cc = (threadIdx.x & 15) * 4;
#pragma unroll
  for (int i = 0; i < 4; i++) {
    int row = rr + i * 16;
    float4 v = *(const float4*)&src[(size_t)(tk + row) * 512 + tn + cc];
    T[(cc + 0) * 65 + row] = f2bf(v.x);
    T[(cc + 1) * 65 + row] = f2bf(v.y);
    T[(cc + 2) * 65 + row] = f2bf(v.z);
    T[(cc + 3) * 65 + row] = f2bf(v.w);
  }
  __syncthreads();
#pragma unroll
  for (int i = 0; i < 4; i++) {
    int n = rr + i * 16;
    ushort4 o;
    o.x = T[n * 65 + cc + 0]; o.y = T[n * 65 + cc + 1];
    o.z = T[n * 65 + cc + 2]; o.w = T[n * 65 + cc + 3];
    *(ushort4*)&dst[(size_t)(tn + n) * 512 + tk + cc] = o;
  }
}

// ---- all 5 projections, fused fp32-A conversion (T14 reg-staging): grid (64, 20).
// A read as fp32, converted in-reg, ds_write'd late; B (bf16 W^T) via gld16.
// Per K-step: issue A-loads(kt+1)+B-gld16(kt+1) -> compute(kt) -> cvt+write(kt+1)
// -> ONE barrier.  CS scale applied at the Q epilogue (was on Wq pre-scale).
__global__ __launch_bounds__(256) void proj_all(
    const float* __restrict__ xqf, const float* __restrict__ xkf,
    const float* __restrict__ xvf,
    const unsigned short* __restrict__ Wq, const unsigned short* __restrict__ Wk,
    const unsigned short* __restrict__ Wv,
    unsigned short* __restrict__ Qo, unsigned short* __restrict__ XKo,
    unsigned short* __restrict__ XVo, unsigned short* __restrict__ Ko,
    unsigned short* __restrict__ Vto) {
  __shared__ unsigned short As[2][128 * 32];
  __shared__ unsigned short Bs[2][128 * 32];
  const int rowBlk = blockIdx.x * 128;
  const int y = blockIdx.y;
  const float* Af; const unsigned short* Bt; int colBlk; int mode;
  float osc = 1.0f;
  unsigned short* out;
  if (y < 12) {
    int wsel = y >> 2;
    Af = xqf; colBlk = (y & 3) * 128; mode = 0;
    Bt = (wsel == 0) ? Wq : (wsel == 1) ? Wk : Wv;
    out = (wsel == 0) ? Qo : (wsel == 1) ? XKo : XVo;
    if (wsel == 0) osc = CS;
  } else if (y < 16) {
    Af = xkf; Bt = Wk; out = Ko; colBlk = (y - 12) * 128; mode = 0;
  } else {
    Af = xvf; Bt = Wv; out = Vto; colBlk = (y - 16) * 128; mode = 1;
  }
  const int t = threadIdx.x;
  const int lane = t & 63, c = lane & 15, g = lane >> 4;
  const int w = t >> 6;
  const int wm = w & 1, wn = w >> 1;
  f32x4 acc[4][4];
#pragma unroll
  for (int i = 0; i < 4; i++)
#pragma unroll
    for (int j = 0; j < 4; j++)
#pragma unroll
      for (int r = 0; r < 4; r++) acc[i][j][r] = 0.f;

  const int sr = t >> 2, sch = t & 3;             // rows sr / sr+64, 8-elem chunk
  const float* pa0 = &Af[(size_t)(rowBlk + sr) * 512 + sch * 8];
  const float* pa1 = &Af[(size_t)(rowBlk + sr + 64) * 512 + sch * 8];

#define LOAD_A(kkk)                                                              \
    va0 = *(const float4*)&pa0[(kkk)];     va1 = *(const float4*)&pa0[(kkk) + 4];\
    va2 = *(const float4*)&pa1[(kkk)];     va3 = *(const float4*)&pa1[(kkk) + 4];
#define STORE_A(buf)                                                             \
  {                                                                              \
    u16x8 u0, u1;                                                                \
    u0[0] = f2bf(va0.x); u0[1] = f2bf(va0.y); u0[2] = f2bf(va0.z);               \
    u0[3] = f2bf(va0.w); u0[4] = f2bf(va1.x); u0[5] = f2bf(va1.y);               \
    u0[6] = f2bf(va1.z); u0[7] = f2bf(va1.w);                                    \
    u1[0] = f2bf(va2.x); u1[1] = f2bf(va2.y); u1[2] = f2bf(va2.z);               \
    u1[3] = f2bf(va2.w); u1[4] = f2bf(va3.x); u1[5] = f2bf(va3.y);               \
    u1[6] = f2bf(va3.z); u1[7] = f2bf(va3.w);                                    \
    *(u16x8*)&As[buf][t * 8] = u0;                                               \
    *(u16x8*)&As[buf][(t + 256) * 8] = u1;                                       \
  }
#define STAGE_B(kkk, buf)                                                        \
  do {                                                                           \
    gld16(&Bt[(size_t)(colBlk + sr) * 512 + (kkk) + sch * 8], &Bs[buf][t * 8]);  \
    gld16(&Bt[(size_t)(colBlk + sr + 64) * 512 + (kkk) + sch * 8],               \
          &Bs[buf][(t + 256) * 8]);                                              \
  } while (0)

  float4 va0, va1, va2, va3;
  // prologue: stage tile 0
  LOAD_A(0);
  STAGE_B(0, 0);
  STORE_A(0);
  __syncthreads();

  for (int kt = 0; kt < 16; kt++) {
    const int cb = kt & 1;
    if (kt < 15) {             // issue next-tile loads early (latency under MFMA)
      LOAD_A((kt + 1) * 32);
      STAGE_B((kt + 1) * 32, cb ^ 1);
    }
    bf16x8 af[4], bfr[4];
#pragma unroll
    for (int i = 0; i < 4; i++)
      af[i] = __builtin_bit_cast(bf16x8, *(const u16x8*)&As[cb][(wm * 64 + i * 16 + c) * 32 + g * 8]);
#pragma unroll
    for (int j = 0; j < 4; j++)
      bfr[j] = __builtin_bit_cast(bf16x8, *(const u16x8*)&Bs[cb][(wn * 64 + j * 16 + c) * 32 + g * 8]);
#pragma unroll
    for (int i = 0; i < 4; i++)
#pragma unroll
      for (int j = 0; j < 4; j++)
        acc[i][j] = __builtin_amdgcn_mfma_f32_16x16x32_bf16(af[i], bfr[j], acc[i][j], 0, 0, 0);
    if (kt < 15) {
      STORE_A(cb ^ 1);         // write-late: vmcnt wait lands after compute
      __syncthreads();
    }
  }
#undef LOAD_A
#undef STORE_A
#undef STAGE_B

  if (mode == 0) {
#pragma unroll
    for (int i = 0; i < 4; i++)
#pragma unroll
      for (int j = 0; j < 4; j++)
#pragma unroll
        for (int r = 0; r < 4; r++) {
          int row = rowBlk + wm * 64 + i * 16 + g * 4 + r;
          int col = colBlk + wn * 64 + j * 16 + c;
          out[(size_t)row * 512 + col] = f2bf(acc[i][j][r] * osc);
        }
  } else {
    // Vt[b][h][dh][n]: acc[i][j][0..3] are 4 consecutive tokens n at fixed dh
#pragma unroll
    for (int i = 0; i < 4; i++) {
      int tok0 = rowBlk + wm * 64 + i * 16 + g * 4;   // tokens tok0..tok0+3
      int bb = tok0 >> 11, n0 = tok0 & 2047;
#pragma unroll
      for (int j = 0; j < 4; j++) {
        int col = colBlk + wn * 64 + j * 16 + c;       // h*64+dh
        int hh = col >> 6, dh = col & 63;
        ushort4 o;
        o.x = f2bf(acc[i][j][0]); o.y = f2bf(acc[i][j][1]);
        o.z = f2bf(acc[i][j][2]); o.w = f2bf(acc[i][j][3]);
        *(ushort4*)&out[((size_t)(bb * 8 + hh) * 64 + dh) * 2048 + n0] = o;
      }
    }
  }
}

// ---- out GEMM: Ob @ Wo^T + bias -> f32: 128x64 tiles, double-buffered ----
__global__ __launch_bounds__(256) void gemm_out(
    const unsigned short* __restrict__ A, const unsigned short* __restrict__ Bt,
    float* __restrict__ out, const float* __restrict__ bias) {
  __shared__ unsigned short As[2 * 128 * 32];
  __shared__ unsigned short Bs[2 * 64 * 32];
  const int rowBlk = blockIdx.x * 128;
  const int colBlk = blockIdx.y * 64;
  const int t = threadIdx.x;
  const int lane = t & 63, c = lane & 15, g = lane >> 4;
  const int w = t >> 6;
  const int wm = w & 1, wn = w >> 1;   // waves 2x2 over (64 rows x 32 cols)
  f32x4 acc[4][2];
#pragma unroll
  for (int i = 0; i < 4; i++)
#pragma unroll
    for (int j = 0; j < 2; j++)
#pragma unroll
      for (int r = 0; r < 4; r++) acc[i][j][r] = 0.f;

  const int sr = t >> 2, sch = t & 3;
#define STAGE_OUT(kkk, buf)                                                      \
  do {                                                                           \
    unsigned short* Ad = As + (buf) * (128 * 32);                                \
    unsigned short* Bd = Bs + (buf) * (64 * 32);                                 \
    gld16(&A[(size_t)(rowBlk + sr) * 512 + (kkk) + sch * 8], &Ad[t * 8]);        \
    gld16(&A[(size_t)(rowBlk + sr + 64) * 512 + (kkk) + sch * 8],                \
          &Ad[(t + 256) * 8]);                                                   \
    gld16(&Bt[(size_t)(colBlk + sr) * 512 + (kkk) + sch * 8], &Bd[t * 8]);       \
  } while (0)

  STAGE_OUT(0, 0);
  __syncthreads();

  for (int kt = 0; kt < 16; kt++) {
    if (kt < 15) STAGE_OUT((kt + 1) * 32, (kt + 1) & 1);
    const unsigned short* Ac = As + (kt & 1) * (128 * 32);
    const unsigned short* Bc = Bs + (kt & 1) * (64 * 32);
    bf16x8 af[4], bfr[2];
#pragma unroll
    for (int i = 0; i < 4; i++)
      af[i] = __builtin_bit_cast(bf16x8, *(const u16x8*)&Ac[(wm * 64 + i * 16 + c) * 32 + g * 8]);
#pragma unroll
    for (int j = 0; j < 2; j++)
      bfr[j] = __builtin_bit_cast(bf16x8, *(const u16x8*)&Bc[(wn * 32 + j * 16 + c) * 32 + g * 8]);
#pragma unroll
    for (int i = 0; i < 4; i++)
#pragma unroll
      for (int j = 0; j < 2; j++)
        acc[i][j] = __builtin_amdgcn_mfma_f32_16x16x32_bf16(af[i], bfr[j], acc[i][j], 0, 0, 0);
    if (kt < 15) __syncthreads();
  }
#undef STAGE_OUT
#pragma unroll
  for (int i = 0; i < 4; i++)
#pragma unroll
    for (int j = 0; j < 2; j++)
#pragma unroll
      for (int r = 0; r < 4; r++) {
        int row = rowBlk + wm * 64 + i * 16 + g * 4 + r;
        int col = colBlk + wn * 32 + j * 16 + c;
        out[(size_t)row * 512 + col] = acc[i][j][r] + bias[col];
      }
}

// ---- fused flash attention v8 (UNCHANGED from round 6, verified): split-K x2.
__global__ __launch_bounds__(512, 2) void attn_kernel(
    const unsigned short* __restrict__ Q, const unsigned short* __restrict__ K,
    const unsigned short* __restrict__ Vt, const unsigned short* __restrict__ XK,
    const unsigned short* __restrict__ XV, unsigned short* __restrict__ O) {
  __shared__ unsigned short Ks[2][2][64 * 64];   // [khalf][dbuf][key][dh-slot]
  __shared__ unsigned short Vs[2][2][64 * 64];   // [khalf][dbuf][dh][key-slot]
  __shared__ float Fin[4][2][32];                // per-q-wave epilogue broadcast
  const int t = threadIdx.x;
  const int w = t >> 6, lane = t & 63;
  const int w01 = w & 3, wk = w >> 2;
  const int rowA = lane & 31, hi = lane >> 5, l7 = lane & 7;
  const int id = blockIdx.x;                     // 512 blocks; XCD = id&7 = h
  const int h = id & 7, qt = (id >> 3) & 15, b = id >> 7;
  const size_t hb = (size_t)b * (2048 * 512) + h * 64;
  const size_t vhb = (size_t)(b * 8 + h) * 64 * 2048;
  const int qb0 = qt * 128 + w01 * 32;

  // staging: thread t -> row sr, swizzled 8-elem slot (sch ^ sr&7)  [v6b proven]
  const int sr = t >> 3, sch = t & 7;
  const int ssl = (sch ^ (sr & 7)) * 8;
  const size_t kgoff = hb + (size_t)sr * 512 + ssl;
  const size_t vgoff = vhb + (size_t)sr * 2048 + ssl;

  // Q fragments (B-operand): Q[q = qb0+rowA][dh = d*16 + hi*8 + e]
  bf16x8 qf[4];
#pragma unroll
  for (int d = 0; d < 4; d++)
    qf[d] = __builtin_bit_cast(bf16x8,
        *(const u16x8*)&Q[hb + (size_t)(qb0 + rowA) * 512 + d * 16 + hi * 8]);

  f32x16 accO[2];
#pragma unroll
  for (int n = 0; n < 2; n++)
#pragma unroll
    for (int r = 0; r < 16; r++) accO[n][r] = 0.f;
  float lq = 0.f;

  // prologue: stage tile 0 (half 0) and tile 16 (half 1) into dbuf 0
  gld16(&K[kgoff], &Ks[0][0][t * 8]);
  gld16(&K[kgoff + (size_t)16 * (64 * 512)], &Ks[1][0][t * 8]);
  gld16(&Vt[vgoff], &Vs[0][0][t * 8]);
  gld16(&Vt[vgoff + 16 * 64], &Vs[1][0][t * 8]);
  __syncthreads();

  for (int kt = 0; kt < 16; kt++) {
    const int cb = kt & 1;
    if (kt < 15) {
      gld16(&K[kgoff + (size_t)(kt + 1) * (64 * 512)], &Ks[0][cb ^ 1][t * 8]);
      gld16(&K[kgoff + (size_t)(kt + 17) * (64 * 512)], &Ks[1][cb ^ 1][t * 8]);
      gld16(&Vt[vgoff + (size_t)(kt + 1) * 64], &Vs[0][cb ^ 1][t * 8]);
      gld16(&Vt[vgoff + (size_t)(kt + 17) * 64], &Vs[1][cb ^ 1][t * 8]);
    }
    const unsigned short* Kc = &Ks[wk][cb][0];
    const unsigned short* Vc = &Vs[wk][cb][0];

    // QK^T: s0 = keys 0-31, s1 = keys 32-63 of this wave's tile; q = rowA
    f32x16 s0, s1;
#pragma unroll
    for (int r = 0; r < 16; r++) { s0[r] = 0.f; s1[r] = 0.f; }
    __builtin_amdgcn_s_setprio(1);
#pragma unroll
    for (int d = 0; d < 4; d++) {
      bf16x8 k0 = __builtin_bit_cast(bf16x8,
          *(const u16x8*)&Kc[rowA * 64 + (((d * 2 + hi) ^ l7) * 8)]);
      s0 = __builtin_amdgcn_mfma_f32_32x32x16_bf16(k0, qf[d], s0, 0, 0, 0);
    }
#pragma unroll
    for (int d = 0; d < 4; d++) {
      bf16x8 k1 = __builtin_bit_cast(bf16x8,
          *(const u16x8*)&Kc[(32 + rowA) * 64 + (((d * 2 + hi) ^ l7) * 8)]);
      s1 = __builtin_amdgcn_mfma_f32_32x32x16_bf16(k1, qf[d], s1, 0, 0, 0);
    }
    __builtin_amdgcn_s_setprio(0);

    // exp in place + row-partial sum (lane-local; q fixed per lane)
    float sum = 0.f;
#pragma unroll
    for (int r = 0; r < 16; r++) { s0[r] = fexp2(s0[r]); sum += s0[r]; }
#pragma unroll
    for (int r = 0; r < 16; r++) { s1[r] = fexp2(s1[r]); sum += s1[r]; }
    lq += sum;

    // P->A-frag (pkr + permlane32_swap) and PV, per 32-key sub-tile
#define PVSUB(P, T2)                                                            \
  {                                                                             \
    unsigned int x0 = pkr(P[0], P[1]),   y0 = pkr(P[4], P[5]);                  \
    unsigned int x1 = pkr(P[2], P[3]),   y1 = pkr(P[6], P[7]);                  \
    unsigned int x2 = pkr(P[8], P[9]),   y2 = pkr(P[12], P[13]);                \
    unsigned int x3 = pkr(P[10], P[11]), y3 = pkr(P[14], P[15]);                \
    PLSWAP(x0, y0); PLSWAP(x1, y1); PLSWAP(x2, y2); PLSWAP(x3, y3);             \
    uint4 w0 = {x0, x1, y0, y1};                                                \
    uint4 w1 = {x2, x3, y2, y3};                                                \
    bf16x8 pa0 = __builtin_bit_cast(bf16x8, w0);                                \
    bf16x8 pa1 = __builtin_bit_cast(bf16x8, w1);                                \
    _Pragma("unroll")                                                           \
    for (int n = 0; n < 2; n++) {                                               \
      bf16x8 v0 = __builtin_bit_cast(bf16x8,                                    \
          *(const u16x8*)&Vc[(n * 32 + rowA) * 64 + ((((T2) * 4 + hi) ^ l7) * 8)]); \
      bf16x8 v1 = __builtin_bit_cast(bf16x8,                                    \
          *(const u16x8*)&Vc[(n * 32 + rowA) * 64 + ((((T2) * 4 + 2 + hi) ^ l7) * 8)]); \
      accO[n] = __builtin_amdgcn_mfma_f32_32x32x16_bf16(pa0, v0, accO[n], 0, 0, 0); \
      accO[n] = __builtin_amdgcn_mfma_f32_32x32x16_bf16(pa1, v1, accO[n], 0, 0, 0); \
    }                                                                           \
  }
    __builtin_amdgcn_s_setprio(1);
    PVSUB(s0, 0);
    PVSUB(s1, 1);
    __builtin_amdgcn_s_setprio(0);
#undef PVSUB

    if (kt < 15) __syncthreads();
  }

  // all waves done reading K/V LDS before the merge overwrites it
  __syncthreads();

  // ---- split-K merge: wk=1 deposits into dead K/V LDS, wk=0 accumulates ----
  {
    float* MB = (w01 < 2) ? (float*)&Ks[0][0][0] : (float*)&Vs[0][0][0];
    const int mbase = ((w01 & 1) * 64 + lane) * 33;   // stride 33: lane->bank spread
    if (wk == 1) {
#pragma unroll
      for (int n = 0; n < 2; n++)
#pragma unroll
        for (int reg = 0; reg < 16; reg++) MB[mbase + n * 16 + reg] = accO[n][reg];
      MB[mbase + 32] = lq;
    }
    __syncthreads();
    if (wk == 1) return;   // wave-uniform exit; no barriers after this point
#pragma unroll
    for (int n = 0; n < 2; n++)
#pragma unroll
      for (int reg = 0; reg < 16; reg++) accO[n][reg] += MB[mbase + n * 16 + reg];
    lq += MB[mbase + 32];
  }

  // finish row-sum: other hi-half holds the remaining keys' partials
  lq += __shfl_xor(lq, 32);

  // diagonal term: q . xq_k over dh=64 ONLY; split by hi (32 elems each)
  float part = 0.f;
  {
    const size_t base = hb + (size_t)(qb0 + rowA) * 512 + hi * 32;
#pragma unroll
    for (int ii = 0; ii < 4; ii++) {
      u16x8 q8 = *(const u16x8*)&Q[base + ii * 8];
      u16x8 x8 = *(const u16x8*)&XK[base + ii * 8];
#pragma unroll
      for (int e = 0; e < 8; e++) part += bf2f(q8[e]) * bf2f(x8[e]);
    }
  }
  part += __shfl_xor(part, 32);
  float pd = fexp2(part);
  float inv = 1.f / (lq + pd);
  if (lane < 32) {
    Fin[w01][0][rowA] = inv;
    Fin[w01][1][rowA] = pd * inv;
  }
  __builtin_amdgcn_s_waitcnt(0);   // per-wave LDS RAW (same-wave ordering)

  f32x4 inva[4], pia[4];
#pragma unroll
  for (int rq = 0; rq < 4; rq++) {
    inva[rq] = *(const f32x4*)&Fin[w01][0][rq * 8 + hi * 4];
    pia[rq]  = *(const f32x4*)&Fin[w01][1][rq * 8 + hi * 4];
  }
#pragma unroll
  for (int n = 0; n < 2; n++)
#pragma unroll
    for (int reg = 0; reg < 16; reg++) {
      const int rq = reg >> 2, r = reg & 3;
      const int q = rq * 8 + hi * 4 + r;          // crow(reg, hi)
      const int qrow = qb0 + q;
      float xv = bf2f(XV[hb + (size_t)qrow * 512 + n * 32 + rowA]);
      float val = accO[n][reg] * inva[rq][r] + pia[rq][r] * xv;
      O[((size_t)(b * 2048 + qrow)) * 512 + h * 64 + n * 32 + rowA] = f2bf(val);
    }
}

extern "C" void kernel_launch(void* const* d_in, const int* in_sizes, int n_in,
                              void* d_out, int out_size, void* d_ws, size_t ws_size,
                              hipStream_t stream) {
  const float* xq = (const float*)d_in[0];
  const float* xk = (const float*)d_in[1];
  const float* xv = (const float*)d_in[2];
  const float* Wq = (const float*)d_in[3];
  const float* Wk = (const float*)d_in[4];
  const float* Wv = (const float*)d_in[5];
  const float* Wo = (const float*)d_in[6];
  const float* bo = (const float*)d_in[7];

  unsigned short* ws = (unsigned short*)d_ws;
  const size_t MD = 8192ull * 512;
  const size_t WD = 512ull * 512;
  unsigned short* Wq_t = ws;
  unsigned short* Wk_t = Wq_t + WD;
  unsigned short* Wv_t = Wk_t + WD;
  unsigned short* Wo_t = Wv_t + WD;
  unsigned short* Qb  = Wo_t + WD;
  unsigned short* Kb  = Qb + MD;
  unsigned short* Vtb = Kb + MD;
  unsigned short* XKb = Vtb + MD;
  unsigned short* XVb = XKb + MD;
  unsigned short* Ob  = XVb + MD;
  // 6*MD + 4*WD elems = ~52 MB

  conv_w<<<dim3(256), 256, 0, stream>>>(Wq, Wk, Wv, Wo, Wq_t, Wk_t, Wv_t, Wo_t);
  proj_all<<<dim3(64, 20), 256, 0, stream>>>(xq, xk, xv, Wq_t, Wk_t, Wv_t,
                                             Qb, XKb, XVb, Kb, Vtb);
  attn_kernel<<<dim3(512), 512, 0, stream>>>(Qb, Kb, Vtb, XKb, XVb, Ob);
  gemm_out<<<dim3(64, 8), 256, 0, stream>>>(Ob, Wo_t, (float*)d_out, bo);
}